// Round 3
// baseline (293.679 us; speedup 1.0000x reference)
//
#include <hip/hip_runtime.h>

// SuperLoss: l = BCE(p,t); y = 0.5*max(-2/e,(l-tau)/lam); w = LambertW(y);
// loss = (l-tau)*sigma + lam*w^2 ; out = sum(loss)/32
//
// R1: 110us, VALUBusy 75% (17 trans/elem). R2: cut to 8 trans/elem ->
// VALUBusy 45%, dur UNCHANGED 110us -> latency-bound, not issue-bound.
// Diagnosis: 2 loads/iter + vmcnt(0) + ~500cy compute exposes ~700cy of
// memory latency every iteration (stall fraction ~55% = 1-VALUBusy).
// R3: software-pipelined register double-buffer - prefetch next group's
// 8 x float4 while computing current group's 16 elements (~2000cy of
// compute covers the in-flight loads).
//
// Math (unchanged from R2, absmax was 0.0):
//  - sigma = exp(-W(y)) == W(y)/y; unclamped loss = 0.9*w*(w+2) (exp-free)
//  - clamped (y<-1/e): closed form lt*e + 0.9 via select
//  - Halley single-rcp form, 2 iterations, 3-term branch-series init for y<0

#define TAU_F       1.5f
#define LAM_F       0.9f
#define E_F         2.718281828459045f
#define NEG_INV_E_F -0.36787944117144233f
#define INV_2LAM_F  0.5555555555555556f    // 1/(2*0.9)
#define LOG2E_F     1.4426950408889634f
#define LN2_F       0.6931471805599453f

__device__ __forceinline__ float fexp2(float x) { return __builtin_amdgcn_exp2f(x); }
__device__ __forceinline__ float flog2(float x) { return __builtin_amdgcn_logf(x); }
__device__ __forceinline__ float frcp(float x)  { return __builtin_amdgcn_rcpf(x); }
__device__ __forceinline__ float fsqrt(float x) { return __builtin_amdgcn_sqrtf(x); }

__device__ __forceinline__ float superloss_elem(float p, float t) {
    // BCE: l = -LN2*(lg1p + t*(lgp - lg1p)); -100 clamp inactive for p in [1e-6,1-1e-6]
    float lgp  = flog2(p);
    float lg1p = flog2(1.0f - p);
    float l    = -LN2_F * fmaf(t, lgp - lg1p, lg1p);
    float lt   = l - TAU_F;
    float y    = lt * INV_2LAM_F;
    bool  clamped = (y < NEG_INV_E_F);
    float yc   = fmaxf(y, NEG_INV_E_F);

    // init: y<0 -> branch series; y>=0 -> log1p
    float s     = fsqrt(fmaxf(fmaf(2.0f * E_F, yc, 2.0f), 0.0f));
    float w_neg = fmaf(s, fmaf(s, fmaf(s, 11.0f / 72.0f, -1.0f / 3.0f), 1.0f), -1.0f);
    float w_pos = LN2_F * flog2(1.0f + yc);
    float w     = (yc < 0.0f) ? w_neg : w_pos;

    // 2 Halley iterations, single-rcp form
    #pragma unroll
    for (int i = 0; i < 2; ++i) {
        float ew   = fexp2(w * LOG2E_F);
        float f    = fmaf(w, ew, -yc);
        float wp1  = w + 1.0f;
        float num  = 2.0f * f * wp1;
        float den  = fmaf(2.0f * ew, wp1 * wp1, -(w + 2.0f) * f) + 1e-12f;
        w = w - num * frcp(den);
    }

    float loss_un = LAM_F * (w * (w + 2.0f));
    float loss_cl = fmaf(lt, E_F, LAM_F);
    return clamped ? loss_cl : loss_un;
}

__device__ __forceinline__ float elem4(float4 p, float4 t) {
    return superloss_elem(p.x, t.x) + superloss_elem(p.y, t.y)
         + superloss_elem(p.z, t.z) + superloss_elem(p.w, t.w);
}

__global__ __launch_bounds__(256) void superloss_kernel(
        const float4* __restrict__ p4, const float4* __restrict__ t4,
        float* __restrict__ out, int n4, int n_tail, const float* __restrict__ p_s,
        const float* __restrict__ t_s) {
    int idx    = blockIdx.x * blockDim.x + threadIdx.x;
    int stride = gridDim.x * blockDim.x;
    int step   = 4 * stride;
    float acc  = 0.0f;

    int i = idx;
    if (i + 3 * stride < n4) {
        // prologue: load group 0
        float4 pa[4], ta[4];
        #pragma unroll
        for (int u = 0; u < 4; ++u) { pa[u] = p4[i + u * stride]; ta[u] = t4[i + u * stride]; }
        i += step;

        // steady state: prefetch group g+1, compute group g
        for (; i + 3 * stride < n4; i += step) {
            float4 pb[4], tb[4];
            #pragma unroll
            for (int u = 0; u < 4; ++u) { pb[u] = p4[i + u * stride]; tb[u] = t4[i + u * stride]; }
            #pragma unroll
            for (int u = 0; u < 4; ++u) acc += elem4(pa[u], ta[u]);
            #pragma unroll
            for (int u = 0; u < 4; ++u) { pa[u] = pb[u]; ta[u] = tb[u]; }
        }
        // epilogue: compute last group
        #pragma unroll
        for (int u = 0; u < 4; ++u) acc += elem4(pa[u], ta[u]);
    }
    // cleanup (empty for n4 % (4*stride) == 0, which holds for this shape)
    for (; i < n4; i += stride) acc += elem4(p4[i], t4[i]);

    if (idx == 0) {   // scalar tail (n % 4)
        for (int k = 4 * n4; k < 4 * n4 + n_tail; ++k)
            acc += superloss_elem(p_s[k], t_s[k]);
    }

    // wave64 shuffle reduction
    #pragma unroll
    for (int off = 32; off > 0; off >>= 1)
        acc += __shfl_down(acc, off, 64);

    __shared__ float wsum[4];
    int lane = threadIdx.x & 63;
    int wid  = threadIdx.x >> 6;
    if (lane == 0) wsum[wid] = acc;
    __syncthreads();
    if (threadIdx.x == 0) {
        float sblk = (wsum[0] + wsum[1]) + (wsum[2] + wsum[3]);
        atomicAdd(out, sblk * (1.0f / 32.0f));   // /BATCH_SIZE
    }
}

extern "C" void kernel_launch(void* const* d_in, const int* in_sizes, int n_in,
                              void* d_out, int out_size, void* d_ws, size_t ws_size,
                              hipStream_t stream) {
    const float* logits  = (const float*)d_in[0];
    const float* targets = (const float*)d_in[1];
    float* out = (float*)d_out;
    int n  = in_sizes[0];
    int n4 = n / 4;
    int n_tail = n - 4 * n4;

    // d_out re-poisoned to 0xAA before every timed launch -> zero it
    hipMemsetAsync(d_out, 0, sizeof(float), stream);

    const int block = 256;
    const int grid  = 2048;   // 524288 threads -> exactly 16 float4-iters/thread
    superloss_kernel<<<grid, block, 0, stream>>>(
        (const float4*)logits, (const float4*)targets, out, n4, n_tail,
        logits, targets);
}

// Round 5
// 267.406 us; speedup vs baseline: 1.0983x; 1.0983x over previous
//
#include <hip/hip_runtime.h>

// SuperLoss: l = BCE(p,t); y = 0.5*max(-2/e,(l-tau)/lam); w = LambertW(y);
// loss = (l-tau)*sigma + lam*w^2 ; out = sum(loss)/32
//
// History: R1 110us VALUBusy 75% (17 trans/elem). R2 (8 trans/elem) 110us
// VALUBusy 45%. R3 (reg double-buffer ILP) 115us VALUBusy 37%, occ 39%.
// All three pinned at ~110us while VALU busy-time fell 82->43us => hard
// memory-system wall at ~2.4 TB/s combined (268MB total, only 131MB from
// HBM, rest "served" by L3). Working set 268MB vs 256MB L3 => capacity
// thrash on the L3 fill path. Data has zero reuse -> mark loads
// non-temporal (nt) so lines bypass cache insertion instead of thrashing.
//
// R5 = R4 with the compile fix: __builtin_nontemporal_load requires a
// NATIVE clang vector type, not HIP_vector_type -> use ext_vector_type(4).
//
// Math (absmax 0.0 in R2/R3):
//  - sigma = exp(-W(y)) == W(y)/y; unclamped loss = 0.9*w*(w+2) (exp-free)
//  - clamped (y<-1/e): closed form lt*e + 0.9 via select
//  - Halley single-rcp form, 2 iterations, 3-term branch-series init

#define TAU_F       1.5f
#define LAM_F       0.9f
#define E_F         2.718281828459045f
#define NEG_INV_E_F -0.36787944117144233f
#define INV_2LAM_F  0.5555555555555556f    // 1/(2*0.9)
#define LOG2E_F     1.4426950408889634f
#define LN2_F       0.6931471805599453f

typedef float floatx4 __attribute__((ext_vector_type(4)));   // native vector: nt-load legal

__device__ __forceinline__ float fexp2(float x) { return __builtin_amdgcn_exp2f(x); }
__device__ __forceinline__ float flog2(float x) { return __builtin_amdgcn_logf(x); }
__device__ __forceinline__ float frcp(float x)  { return __builtin_amdgcn_rcpf(x); }
__device__ __forceinline__ float fsqrt(float x) { return __builtin_amdgcn_sqrtf(x); }

__device__ __forceinline__ float superloss_elem(float p, float t) {
    // BCE: l = -LN2*(lg1p + t*(lgp - lg1p)); -100 clamp inactive for p in [1e-6,1-1e-6]
    float lgp  = flog2(p);
    float lg1p = flog2(1.0f - p);
    float l    = -LN2_F * fmaf(t, lgp - lg1p, lg1p);
    float lt   = l - TAU_F;
    float y    = lt * INV_2LAM_F;
    bool  clamped = (y < NEG_INV_E_F);
    float yc   = fmaxf(y, NEG_INV_E_F);

    // init: y<0 -> branch series; y>=0 -> log1p
    float s     = fsqrt(fmaxf(fmaf(2.0f * E_F, yc, 2.0f), 0.0f));
    float w_neg = fmaf(s, fmaf(s, fmaf(s, 11.0f / 72.0f, -1.0f / 3.0f), 1.0f), -1.0f);
    float w_pos = LN2_F * flog2(1.0f + yc);
    float w     = (yc < 0.0f) ? w_neg : w_pos;

    // 2 Halley iterations, single-rcp form
    #pragma unroll
    for (int i = 0; i < 2; ++i) {
        float ew   = fexp2(w * LOG2E_F);
        float f    = fmaf(w, ew, -yc);
        float wp1  = w + 1.0f;
        float num  = 2.0f * f * wp1;
        float den  = fmaf(2.0f * ew, wp1 * wp1, -(w + 2.0f) * f) + 1e-12f;
        w = w - num * frcp(den);
    }

    float loss_un = LAM_F * (w * (w + 2.0f));
    float loss_cl = fmaf(lt, E_F, LAM_F);
    return clamped ? loss_cl : loss_un;
}

__global__ __launch_bounds__(256) void superloss_kernel(
        const floatx4* __restrict__ p4, const floatx4* __restrict__ t4,
        float* __restrict__ out, int n4, int n_tail, const float* __restrict__ p_s,
        const float* __restrict__ t_s) {
    int idx    = blockIdx.x * blockDim.x + threadIdx.x;
    int stride = gridDim.x * blockDim.x;
    float acc = 0.0f;
    for (int i = idx; i < n4; i += stride) {
        floatx4 p = __builtin_nontemporal_load(&p4[i]);   // nt: bypass L2/L3 insertion
        floatx4 t = __builtin_nontemporal_load(&t4[i]);
        acc += superloss_elem(p.x, t.x);
        acc += superloss_elem(p.y, t.y);
        acc += superloss_elem(p.z, t.z);
        acc += superloss_elem(p.w, t.w);
    }
    if (idx == 0) {   // scalar tail (n % 4) — empty for this shape
        for (int i = 4 * n4; i < 4 * n4 + n_tail; ++i)
            acc += superloss_elem(p_s[i], t_s[i]);
    }

    // wave64 shuffle reduction
    #pragma unroll
    for (int off = 32; off > 0; off >>= 1)
        acc += __shfl_down(acc, off, 64);

    __shared__ float wsum[4];
    int lane = threadIdx.x & 63;
    int wid  = threadIdx.x >> 6;
    if (lane == 0) wsum[wid] = acc;
    __syncthreads();
    if (threadIdx.x == 0) {
        float sblk = (wsum[0] + wsum[1]) + (wsum[2] + wsum[3]);
        atomicAdd(out, sblk * (1.0f / 32.0f));   // /BATCH_SIZE
    }
}

extern "C" void kernel_launch(void* const* d_in, const int* in_sizes, int n_in,
                              void* d_out, int out_size, void* d_ws, size_t ws_size,
                              hipStream_t stream) {
    const float* logits  = (const float*)d_in[0];
    const float* targets = (const float*)d_in[1];
    float* out = (float*)d_out;
    int n  = in_sizes[0];
    int n4 = n / 4;
    int n_tail = n - 4 * n4;

    // d_out re-poisoned to 0xAA before every timed launch -> zero it
    (void)hipMemsetAsync(d_out, 0, sizeof(float), stream);

    const int block = 256;
    const int grid  = 2048;   // 8192 waves; grid-stride, 16 float4-iters/thread
    superloss_kernel<<<grid, block, 0, stream>>>(
        (const floatx4*)logits, (const floatx4*)targets, out, n4, n_tail,
        logits, targets);
}

// Round 6
// 260.890 us; speedup vs baseline: 1.1257x; 1.0250x over previous
//
#include <hip/hip_runtime.h>

// SuperLoss: l = BCE(p,t); y = 0.5*max(-2/e,(l-tau)/lam); w = LambertW(y);
// loss = (l-tau)*sigma + lam*w^2 ; out = sum(loss)/32
//
// History: R1 110us VALUBusy 75% (17 trans/elem). R2 (8 trans/elem) 110us
// VALUBusy 45% -> latency/L3 wall. R3 ILP pipeline: no help. R5 nt-loads:
// kernel dropped below the harness's 77us fill dispatches (L3-thrash fixed;
// 268MB streaming set vs 256MiB L3 was throttling reads to 2.4TB/s).
// Now compute-bound again (R2 VALU busy-time ~50us vs 43us memory floor).
//
// R6: cut 8 -> 6 trans/elem:
//  - 1 Halley iteration (was 2). Init err <=0.18 (series, y<0) / <=0.3
//    (log1p, y>=0 mid-range); cubic convergence leaves ~1e-4 typical.
//    Budget: threshold 1.9e4 over 3.36e7/32-scaled sum -> 1.8e-2 mean
//    signed error allowed. ~100x margin.
//  - BCE folded straight into y: y = fma(g, -ln2/1.8, -1.5/1.8),
//    clamped closed form loss = y*(1.8e) + 0.9 (uses y, not lt).
//  - sigma = exp(-W) == W/y identity -> unclamped loss = 0.9*w*(w+2).
// Per elem: 2 log (BCE) + log (init) + sqrt + exp + rcp = 6 quarter-rate.

#define E_F         2.718281828459045f
#define NEG_INV_E_F -0.36787944117144233f
#define A_COEF      -0.38508176972343707f   // -ln2 / 1.8
#define B_COEF      -0.8333333333333333f    // -1.5 / 1.8
#define CL_SLOPE    4.892907291226281f      // 1.8 * e
#define LOG2E_F     1.4426950408889634f
#define LN2_F       0.6931471805599453f

typedef float floatx4 __attribute__((ext_vector_type(4)));

__device__ __forceinline__ float fexp2(float x) { return __builtin_amdgcn_exp2f(x); }
__device__ __forceinline__ float flog2(float x) { return __builtin_amdgcn_logf(x); }
__device__ __forceinline__ float frcp(float x)  { return __builtin_amdgcn_rcpf(x); }
__device__ __forceinline__ float fsqrt(float x) { return __builtin_amdgcn_sqrtf(x); }

__device__ __forceinline__ float superloss_elem(float p, float t) {
    // g = log2-space BCE: l = -LN2*g ; y = (l-1.5)/1.8 = A*g + B
    float lgp  = flog2(p);
    float lg1p = flog2(1.0f - p);
    float g    = fmaf(t, lgp - lg1p, lg1p);
    float y    = fmaf(g, A_COEF, B_COEF);
    bool  clamped = (y < NEG_INV_E_F);
    float yc   = fmaxf(y, NEG_INV_E_F);

    // Lambert W init: y<0 -> 3-term branch series in s; y>=0 -> log1p
    float s     = fsqrt(fmaxf(fmaf(2.0f * E_F, yc, 2.0f), 0.0f));
    float w_neg = fmaf(s, fmaf(s, fmaf(s, 11.0f / 72.0f, -1.0f / 3.0f), 1.0f), -1.0f);
    float w_pos = LN2_F * flog2(1.0f + yc);
    float w     = (yc < 0.0f) ? w_neg : w_pos;

    // 1 Halley iteration, single-rcp form
    {
        float ew   = fexp2(w * LOG2E_F);
        float f    = fmaf(w, ew, -yc);
        float wp1  = w + 1.0f;
        float num  = 2.0f * f * wp1;
        float den  = fmaf(2.0f * ew, wp1 * wp1, -(w + 2.0f) * f) + 1e-12f;
        w = w - num * frcp(den);
    }

    // unclamped: 0.9*w*(w+2); clamped: 1.8e*y + 0.9
    float loss_un = 0.9f * (w * (w + 2.0f));
    float loss_cl = fmaf(y, CL_SLOPE, 0.9f);
    return clamped ? loss_cl : loss_un;
}

__global__ __launch_bounds__(256) void superloss_kernel(
        const floatx4* __restrict__ p4, const floatx4* __restrict__ t4,
        float* __restrict__ out, int n4, int n_tail, const float* __restrict__ p_s,
        const float* __restrict__ t_s) {
    int idx    = blockIdx.x * blockDim.x + threadIdx.x;
    int stride = gridDim.x * blockDim.x;
    float acc = 0.0f;
    for (int i = idx; i < n4; i += stride) {
        floatx4 p = __builtin_nontemporal_load(&p4[i]);   // nt: bypass L2/L3 insertion
        floatx4 t = __builtin_nontemporal_load(&t4[i]);
        acc += superloss_elem(p.x, t.x);
        acc += superloss_elem(p.y, t.y);
        acc += superloss_elem(p.z, t.z);
        acc += superloss_elem(p.w, t.w);
    }
    if (idx == 0) {   // scalar tail (n % 4) — empty for this shape
        for (int i = 4 * n4; i < 4 * n4 + n_tail; ++i)
            acc += superloss_elem(p_s[i], t_s[i]);
    }

    // wave64 shuffle reduction
    #pragma unroll
    for (int off = 32; off > 0; off >>= 1)
        acc += __shfl_down(acc, off, 64);

    __shared__ float wsum[4];
    int lane = threadIdx.x & 63;
    int wid  = threadIdx.x >> 6;
    if (lane == 0) wsum[wid] = acc;
    __syncthreads();
    if (threadIdx.x == 0) {
        float sblk = (wsum[0] + wsum[1]) + (wsum[2] + wsum[3]);
        atomicAdd(out, sblk * (1.0f / 32.0f));   // /BATCH_SIZE
    }
}

extern "C" void kernel_launch(void* const* d_in, const int* in_sizes, int n_in,
                              void* d_out, int out_size, void* d_ws, size_t ws_size,
                              hipStream_t stream) {
    const float* logits  = (const float*)d_in[0];
    const float* targets = (const float*)d_in[1];
    float* out = (float*)d_out;
    int n  = in_sizes[0];
    int n4 = n / 4;
    int n_tail = n - 4 * n4;

    // d_out re-poisoned to 0xAA before every timed launch -> zero it
    (void)hipMemsetAsync(d_out, 0, sizeof(float), stream);

    const int block = 256;
    const int grid  = 2048;   // 8192 waves; grid-stride, 16 float4-iters/thread
    superloss_kernel<<<grid, block, 0, stream>>>(
        (const floatx4*)logits, (const floatx4*)targets, out, n4, n_tail,
        logits, targets);
}